// Round 11
// baseline (111.163 us; speedup 1.0000x reference)
//
#include <hip/hip_runtime.h>
#include <math.h>

// ---- problem constants ----
#define WAV_N     262144
#define HOP       128
#define MIN_WIN   16699
#define LEFT      24418            // (65536 - 16699)/2
#define T_FRAMES  2049
#define N_BINS    96
#define N_CQCC    20
#define F_COMP    192              // 96 bins x {lo,hi}
#define NF        576              // 192 comps x 3 Hann planes
#define NBLK      2179             // 128-sample chunks covering padded signal
#define NBP       2240             // padded b-dim for QFP rows (= 35*64)
#define PARTLEN   59               // 16699 - 130*128
#define FULLBLK   130
#define XS_VALID  278843           // 2048*128 + 16699
#define TWOPI     6.283185307179586f

// ---- chunk kernel tiling: 630 blocks (35 x 18), 256 thr = 32 f x 8 bg x 8 b ----
#define BT   64
#define FTW  32
#define AST  68                    // A_lds row stride (272 B = 17x16B: b128-aligned rows)

// ---- workspace layout (bytes) ----
#define WS_QFP  0                  // 576*2240*16 = 20,643,840  float4(qf.re,qf.im,qp.re,qp.im)
#define WS_V    20643840           // 576*2056*8  =  9,474,048  rotated V [f][t]
#define WS_CQ   30117888           // 2049*20*4   =    163,920
#define WS_SUMS 30281808           // 40 doubles
#define VTP     2056               // V row stride (float2 units)

// f = plane*192 + c; c = bin*2 + hi; replicate reference f32 arithmetic for floor()
__device__ __forceinline__ void f_to_fi_sigma(int f, int& fi, int& sigma) {
    int plane = f / 192;
    int c = f - plane * 192;
    int bin = c >> 1, hi = c & 1;
    float e    = (float)bin / 24.0f;
    float fb   = 32.7f * exp2f(e);
    float idxf = fb / 8000.0f * 32768.0f;
    fi = (int)idxf + hi;
    sigma = (plane == 0) ? 0 : (plane == 1 ? 1 : -1);
}

// QFP[f][b] = (qf, qp): qf = e^{-i w0} sum_{j<128} xs[128b+j] E[j][f], qp = j<59 version
// 8 b x 1 f per thread: 16 FMA per (2 ds_read_b128 + 6 rotator) -- max FMA density;
// 16 independent FMA chains cover the rotator dep chain even at low occupancy.
__global__ __launch_bounds__(256) void k_chunk(const float* __restrict__ wav,
                                               float4* __restrict__ QFP) {
    __shared__ float A_lds[128 * AST];             // 34,816 B
    int tid = threadIdx.x;
    int b0 = blockIdx.x * BT;
    int f0 = blockIdx.y * FTW;

    // stage full 64b x 128j tile; j-fast mapping keeps global reads coalesced
    {
        int sbase = 128 * b0;
        #pragma unroll
        for (int k = 0; k < 32; ++k) {
            int m = k * 256 + tid;                 // m = 128*bl + j
            int j = m & 127, bl = m >> 7;
            int s = sbase + m;
            float v = 0.0f;
            if (s < XS_VALID) {
                int w = s - 8350;                  // s + LEFT - 32768
                if (w < 0) w = -w;
                if (w >= WAV_N) w = 2 * WAV_N - 2 - w;
                v = wav[w];
            }
            A_lds[j * AST + bl] = v;
        }
    }

    int f   = f0 + (tid & 31);
    int bg  = tid >> 5;                            // 0..7
    int bl0 = bg * 8;
    int bb  = b0 + bl0;

    int fi, sg;
    f_to_fi_sigma(f, fi, sg);

    // rotator step D = e^{-2*pi*i*(fi/65536 - sg/W)}; anchor W = 1 at j=0 (exact)
    float Dr, Di;
    {
        float fr = (float)fi * (1.0f / 65536.0f) - (float)sg * (1.0f / (float)MIN_WIN);
        fr -= rintf(fr);
        float sn, cs; __sincosf(TWOPI * fr, &sn, &cs);
        Dr = cs; Di = -sn;
    }
    float Wr = 1.0f, Wi = 0.0f;

    float xr[8], xi[8], pr[8], pi[8];
    #pragma unroll
    for (int i = 0; i < 8; ++i) { xr[i] = 0.f; xi[i] = 0.f; }

    __syncthreads();

    #pragma unroll 4
    for (int j = 0; j < PARTLEN; ++j) {
        float4 a0 = *(const float4*)&A_lds[j * AST + bl0];
        float4 a1 = *(const float4*)&A_lds[j * AST + bl0 + 4];
        const float aa[8] = {a0.x, a0.y, a0.z, a0.w, a1.x, a1.y, a1.z, a1.w};
        #pragma unroll
        for (int i = 0; i < 8; ++i) {
            xr[i] = fmaf(aa[i], Wr, xr[i]);
            xi[i] = fmaf(aa[i], Wi, xi[i]);
        }
        float wr = Wr;
        Wr = wr * Dr - Wi * Di;
        Wi = wr * Di + Wi * Dr;
    }
    #pragma unroll
    for (int i = 0; i < 8; ++i) { pr[i] = xr[i]; pi[i] = xi[i]; }
    #pragma unroll 4
    for (int j = PARTLEN; j < 128; ++j) {
        float4 a0 = *(const float4*)&A_lds[j * AST + bl0];
        float4 a1 = *(const float4*)&A_lds[j * AST + bl0 + 4];
        const float aa[8] = {a0.x, a0.y, a0.z, a0.w, a1.x, a1.y, a1.z, a1.w};
        #pragma unroll
        for (int i = 0; i < 8; ++i) {
            xr[i] = fmaf(aa[i], Wr, xr[i]);
            xi[i] = fmaf(aa[i], Wi, xi[i]);
        }
        float wr = Wr;
        Wr = wr * Dr - Wi * Di;
        Wi = wr * Di + Wi * Dr;
    }

    // apply e^{-i w0(b,f)}; each lane stores 8 contiguous float4 (2 full sectors)
    float4* dst = QFP + (size_t)f * NBP + bb;
    #pragma unroll
    for (int i = 0; i < 8; ++i) {
        int b = bb + i;
        unsigned ph = ((unsigned)fi * (unsigned)(LEFT + 128 * b)) & 65535u;
        float frf = (float)ph * (1.0f / 65536.0f)
                  - (float)sg * (float)((128 * b) % MIN_WIN) * (1.0f / (float)MIN_WIN);
        frf -= rintf(frf);
        float sn, cs; __sincosf(TWOPI * frf, &sn, &cs);
        dst[i] = make_float4(xr[i] * cs + xi[i] * sn,
                             xi[i] * cs - xr[i] * sn,
                             pr[i] * cs + pi[i] * sn,
                             pi[i] * cs - pr[i] * sn);
    }
}

// one block per f (576 blocks x 512 thr): LDS-resident float4 column, fp64 scan of
// .xy, U = G[t+130]-G[t]+qp[t+130] (qp = .zw, LDS), rotate, write V[f][t] coalesced.
#define SEG 5                      // 512*5 = 2560 >= 2179
__global__ __launch_bounds__(512) void k_scan(const float4* __restrict__ QFP,
                                              float2* __restrict__ V,
                                              double* __restrict__ sums) {
    __shared__ float4 col[NBLK];       // 34,864 B
    __shared__ double2 wsum[8];
    int tid = threadIdx.x;
    int f = blockIdx.x;
    if (f == 0 && tid < 40) sums[tid] = 0.0;   // zero stats accumulators

    const float4* g = QFP + (size_t)f * NBP;
    #pragma unroll
    for (int k = 0; k < SEG; ++k) {
        int idx = k * 512 + tid;
        if (idx < NBLK) col[idx] = g[idx];
    }
    __syncthreads();

    int s0 = tid * SEG, s1 = min(s0 + SEG, NBLK);
    double sr = 0.0, si = 0.0;
    for (int i = s0; i < s1; ++i) { sr += col[i].x; si += col[i].y; }
    double r = sr, im = si;
    #pragma unroll
    for (int off = 1; off < 64; off <<= 1) {
        double prx = __shfl_up(r, off);
        double piy = __shfl_up(im, off);
        if ((tid & 63) >= off) { r += prx; im += piy; }
    }
    if ((tid & 63) == 63) wsum[tid >> 6] = make_double2(r, im);
    __syncthreads();
    double basr = 0.0, basi = 0.0;
    int w = tid >> 6;
    for (int ww = 0; ww < w; ++ww) { basr += wsum[ww].x; basi += wsum[ww].y; }
    double gr = basr + r - sr, gi = basi + im - si;   // exclusive prefix at s0
    for (int i = s0; i < s1; ++i) {
        float qx = col[i].x, qy = col[i].y;
        col[i].x = (float)gr; col[i].y = (float)gi;
        gr += qx; gi += qy;
    }
    __syncthreads();

    int fi_, sg_; f_to_fi_sigma(f, fi_, sg_);
    float2* vrow = V + (size_t)f * VTP;
    #pragma unroll
    for (int k = 0; k < SEG; ++k) {
        int t = k * 512 + tid;
        if (t < T_FRAMES) {
            float4 ca = col[t];
            float4 cb = col[t + FULLBLK];
            float ur = cb.x - ca.x + cb.z;
            float ui = cb.y - ca.y + cb.w;
            unsigned ph = ((unsigned)fi_ * 128u * (unsigned)t) & 65535u;
            float frf = (float)ph * (1.0f / 65536.0f)
                      - (float)sg_ * (float)((128 * t) % MIN_WIN) * (1.0f / (float)MIN_WIN);
            frf -= rintf(frf);
            float sn, cs;
            __sincosf(TWOPI * frf, &sn, &cs);
            vrow[t] = make_float2(ur * cs - ui * sn, ur * sn + ui * cs);
        }
    }
}

// 16 frames/block (129 blocks): fold 3 planes (coalesced V reads along t) -> power
// -> interp -> log -> DCT -> fp64 atomic stats partials
#define TF16 16
__global__ __launch_bounds__(256) void k_cqt(const float2* __restrict__ V,
                                             float* __restrict__ cq,
                                             double* __restrict__ sums) {
    __shared__ float dctm[N_CQCC * N_BINS];     // 7680 B
    __shared__ float2 sc[F_COMP * TF16];        // [c][tl], 24,576 B
    __shared__ float lg[N_BINS * TF16];         // [b][tl], 6144 B
    __shared__ float cqv[N_CQCC * TF16];        // [k][tl], 1280 B
    int tid = threadIdx.x;
    int tb = blockIdx.x * TF16;
    for (int idx = tid; idx < N_CQCC * N_BINS; idx += 256) {
        int k = idx / N_BINS, b = idx - k * N_BINS;
        dctm[idx] = cosf((float)M_PI * (float)(k * (2 * b + 1)) / 192.0f);
    }
    for (int idx = tid; idx < F_COMP * TF16; idx += 256) {
        int c = idx >> 4, tl = idx & 15;
        int t = tb + tl;
        float2 v = make_float2(0.f, 0.f);
        if (t < T_FRAMES) {
            float2 v0 = V[(size_t)c * VTP + t];
            float2 v1 = V[(size_t)(192 + c) * VTP + t];
            float2 v2 = V[(size_t)(384 + c) * VTP + t];
            v = make_float2(0.5f * v0.x - 0.25f * (v1.x + v2.x),
                            0.5f * v0.y - 0.25f * (v1.y + v2.y));
        }
        sc[idx] = v;
    }
    __syncthreads();
    for (int idx = tid; idx < N_BINS * TF16; idx += 256) {
        int b = idx >> 4, tl = idx & 15;
        float2 lo = sc[(2 * b) * TF16 + tl];
        float2 hi = sc[(2 * b + 1) * TF16 + tl];
        float pl = lo.x * lo.x + lo.y * lo.y;
        float ph = hi.x * hi.x + hi.y * hi.y;
        float e    = (float)b / 24.0f;
        float fb   = 32.7f * exp2f(e);
        float idxf = fb / 8000.0f * 32768.0f;
        float alpha = idxf - (float)((int)idxf);
        float p = (1.0f - alpha) * pl + alpha * ph;
        lg[idx] = logf(fmaxf(p, 1e-8f));
    }
    __syncthreads();
    for (int idx = tid; idx < N_CQCC * TF16; idx += 256) {
        int k = idx >> 4, tl = idx & 15;
        int t = tb + tl;
        float s = 0.0f;
        #pragma unroll 4
        for (int b = 0; b < N_BINS; ++b) s += dctm[k * N_BINS + b] * lg[b * TF16 + tl];
        cqv[idx] = (t < T_FRAMES) ? s : 0.0f;
        if (t < T_FRAMES) cq[t * N_CQCC + k] = s;
    }
    __syncthreads();
    if (tid < N_CQCC) {
        double s1 = 0.0, s2 = 0.0;
        #pragma unroll
        for (int tl = 0; tl < TF16; ++tl) {
            if (tb + tl < T_FRAMES) {
                double v = (double)cqv[tid * TF16 + tl];
                s1 += v; s2 += v * v;
            }
        }
        atomicAdd(&sums[tid], s1);
        atomicAdd(&sums[N_CQCC + tid], s2);
    }
}

__device__ __forceinline__ int clampT(int v) {
    return v < 0 ? 0 : (v > T_FRAMES - 1 ? T_FRAMES - 1 : v);
}

// normalize + delta + delta-delta; mean/inv derived inline from fp64 sums
__global__ void k_final(const float* __restrict__ cq, const double* __restrict__ sums,
                        float* __restrict__ out) {
    int gid = blockIdx.x * blockDim.x + threadIdx.x;
    if (gid >= T_FRAMES * N_CQCC) return;
    int t = gid / N_CQCC;
    int k = gid - t * N_CQCC;
    double S1 = sums[k], S2 = sums[N_CQCC + k];
    double md = S1 / (double)T_FRAMES;
    double var = (S2 - S1 * md) / (double)(T_FRAMES - 1);
    double sd = sqrt(var > 0.0 ? var : 0.0);
    float m = (float)md;
    float iv = (float)(1.0 / (sd + 1e-8));
    float cv[9];
    #pragma unroll
    for (int j = 0; j < 9; ++j)
        cv[j] = (cq[clampT(t + j - 4) * N_CQCC + k] - m) * iv;
    float dv[5];
    #pragma unroll
    for (int o = -2; o <= 2; ++o) {
        int p = clampT(t + o);
        int h1 = clampT(p + 1) - t, l1 = clampT(p - 1) - t;
        int h2 = clampT(p + 2) - t, l2 = clampT(p - 2) - t;
        dv[o + 2] = ((cv[h1 + 4] - cv[l1 + 4]) + 2.0f * (cv[h2 + 4] - cv[l2 + 4])) * 0.1f;
    }
    out[t * 60 + k]      = cv[4];
    out[t * 60 + 20 + k] = dv[2];
    out[t * 60 + 40 + k] = (dv[3] - dv[1] + 2.0f * (dv[4] - dv[0])) * 0.1f;
}

extern "C" void kernel_launch(void* const* d_in, const int* in_sizes, int n_in,
                              void* d_out, int out_size, void* d_ws, size_t ws_size,
                              hipStream_t stream) {
    const float* wav = (const float*)d_in[0];
    float* out = (float*)d_out;
    char* ws = (char*)d_ws;
    float4* QFP  = (float4*)(ws + WS_QFP);
    float2* V    = (float2*)(ws + WS_V);
    float*  cq   = (float*)(ws + WS_CQ);
    double* sums = (double*)(ws + WS_SUMS);

    k_chunk<<<dim3(NBP / BT, NF / FTW), 256, 0, stream>>>(wav, QFP);
    k_scan<<<NF, 512, 0, stream>>>(QFP, V, sums);
    k_cqt<<<(T_FRAMES + TF16 - 1) / TF16, 256, 0, stream>>>(V, cq, sums);
    k_final<<<(T_FRAMES * N_CQCC + 255) / 256, 256, 0, stream>>>(cq, sums, out);
}

// Round 12
// 106.737 us; speedup vs baseline: 1.0415x; 1.0415x over previous
//
#include <hip/hip_runtime.h>
#include <math.h>

// ---- problem constants ----
#define WAV_N     262144
#define HOP       128
#define MIN_WIN   16699
#define LEFT      24418            // (65536 - 16699)/2
#define T_FRAMES  2049
#define N_BINS    96
#define N_CQCC    20
#define F_COMP    192              // 96 bins x {lo,hi}
#define NF        576              // 192 comps x 3 Hann planes
#define NBLK      2179             // 128-sample chunks covering padded signal
#define NBP       2240             // padded b-dim for QFP rows (= 70*32)
#define PARTLEN   59               // 16699 - 130*128
#define FULLBLK   130
#define XS_VALID  278843           // 2048*128 + 16699
#define TWOPI     6.283185307179586f

// ---- chunk kernel tiling: 1260 blocks (70 x 18), 256 thr = 32 f x 8 bg x 4 b ----
// r9/r10 sweet spot: 4.9 waves/SIMD. r11's 8b/630-block variant regressed (+4.4us):
// k_chunk is occupancy-limited, not issue-limited -- grid size beats instr density.
#define BT   32
#define FTW  32
#define AST  34                    // A_lds row stride

// ---- workspace layout (bytes) ----
#define WS_QFP  0                  // 576*2240*16 = 20,643,840  float4(qf.re,qf.im,qp.re,qp.im)
#define WS_V    20643840           // 576*2056*8  =  9,474,048  rotated V [f][t]
#define WS_CQ   30117888           // 2049*20*4   =    163,920
#define WS_SUMS 30281808           // 40 doubles
#define VTP     2056               // V row stride (float2 units)

// f = plane*192 + c; c = bin*2 + hi; replicate reference f32 arithmetic for floor()
__device__ __forceinline__ void f_to_fi_sigma(int f, int& fi, int& sigma) {
    int plane = f / 192;
    int c = f - plane * 192;
    int bin = c >> 1, hi = c & 1;
    float e    = (float)bin / 24.0f;
    float fb   = 32.7f * exp2f(e);
    float idxf = fb / 8000.0f * 32768.0f;
    fi = (int)idxf + hi;
    sigma = (plane == 0) ? 0 : (plane == 1 ? 1 : -1);
}

// QFP[f][b] = (qf, qp): qf = e^{-i w0} sum_{j<128} xs[128b+j] E[j][f], qp = j<59 version
__global__ __launch_bounds__(256) void k_chunk(const float* __restrict__ wav,
                                               float4* __restrict__ QFP) {
    __shared__ float A_lds[128 * AST];             // 17,408 B
    int tid = threadIdx.x;
    int b0 = blockIdx.x * BT;
    int f0 = blockIdx.y * FTW;

    // stage full 32b x 128j tile
    {
        int sbase = 128 * b0;
        #pragma unroll
        for (int k = 0; k < 16; ++k) {
            int m = k * 256 + tid;
            int j = m & 127, bl = m >> 7;
            int s = sbase + m;
            float v = 0.0f;
            if (s < XS_VALID) {
                int w = s - 8350;                  // s + LEFT - 32768
                if (w < 0) w = -w;
                if (w >= WAV_N) w = 2 * WAV_N - 2 - w;
                v = wav[w];
            }
            A_lds[j * AST + bl] = v;
        }
    }

    int f  = f0 + (tid & 31);
    int bg = tid >> 5;                             // 0..7
    int bl0 = bg * 4;
    int bb = b0 + bl0;

    int fi, sg;
    f_to_fi_sigma(f, fi, sg);

    // rotator step D = e^{-2*pi*i*(fi/65536 - sg/W)}; anchor W = 1 at j=0 (exact)
    float Dr, Di;
    {
        float fr = (float)fi * (1.0f / 65536.0f) - (float)sg * (1.0f / (float)MIN_WIN);
        fr -= rintf(fr);
        float sn, cs; __sincosf(TWOPI * fr, &sn, &cs);
        Dr = cs; Di = -sn;
    }
    float Wr = 1.0f, Wi = 0.0f;

    float xr[4] = {0, 0, 0, 0}, xi[4] = {0, 0, 0, 0};
    float pr[4], pi[4];

    __syncthreads();

    #pragma unroll 4
    for (int j = 0; j < PARTLEN; ++j) {
        float2 a01 = *(const float2*)&A_lds[j * AST + bl0];
        float2 a23 = *(const float2*)&A_lds[j * AST + bl0 + 2];
        const float aa[4] = {a01.x, a01.y, a23.x, a23.y};
        #pragma unroll
        for (int i = 0; i < 4; ++i) {
            xr[i] = fmaf(aa[i], Wr, xr[i]);
            xi[i] = fmaf(aa[i], Wi, xi[i]);
        }
        float wr = Wr;
        Wr = wr * Dr - Wi * Di;
        Wi = wr * Di + Wi * Dr;
    }
    #pragma unroll
    for (int i = 0; i < 4; ++i) { pr[i] = xr[i]; pi[i] = xi[i]; }
    #pragma unroll 4
    for (int j = PARTLEN; j < 128; ++j) {
        float2 a01 = *(const float2*)&A_lds[j * AST + bl0];
        float2 a23 = *(const float2*)&A_lds[j * AST + bl0 + 2];
        const float aa[4] = {a01.x, a01.y, a23.x, a23.y};
        #pragma unroll
        for (int i = 0; i < 4; ++i) {
            xr[i] = fmaf(aa[i], Wr, xr[i]);
            xi[i] = fmaf(aa[i], Wi, xi[i]);
        }
        float wr = Wr;
        Wr = wr * Dr - Wi * Di;
        Wi = wr * Di + Wi * Dr;
    }

    float4* dst = QFP + (size_t)f * NBP + bb;
    #pragma unroll
    for (int i = 0; i < 4; ++i) {
        int b = bb + i;
        unsigned ph = ((unsigned)fi * (unsigned)(LEFT + 128 * b)) & 65535u;
        float frf = (float)ph * (1.0f / 65536.0f)
                  - (float)sg * (float)((128 * b) % MIN_WIN) * (1.0f / (float)MIN_WIN);
        frf -= rintf(frf);
        float sn, cs; __sincosf(TWOPI * frf, &sn, &cs);
        dst[i] = make_float4(xr[i] * cs + xi[i] * sn,
                             xi[i] * cs - xr[i] * sn,
                             pr[i] * cs + pi[i] * sn,
                             pi[i] * cs - pr[i] * sn);
    }
}

// one block per f (576 blocks x 512 thr): LDS-resident float4 column, fp64 scan of
// .xy, U = G[t+130]-G[t]+qp[t+130] (qp = .zw, LDS), rotate, write V[f][t] coalesced.
#define SEG 5                      // 512*5 = 2560 >= 2179
__global__ __launch_bounds__(512) void k_scan(const float4* __restrict__ QFP,
                                              float2* __restrict__ V,
                                              double* __restrict__ sums) {
    __shared__ float4 col[NBLK];       // 34,864 B
    __shared__ double2 wsum[8];
    int tid = threadIdx.x;
    int f = blockIdx.x;
    if (f == 0 && tid < 40) sums[tid] = 0.0;   // zero stats accumulators

    const float4* g = QFP + (size_t)f * NBP;
    #pragma unroll
    for (int k = 0; k < SEG; ++k) {
        int idx = k * 512 + tid;
        if (idx < NBLK) col[idx] = g[idx];
    }
    __syncthreads();

    int s0 = tid * SEG, s1 = min(s0 + SEG, NBLK);
    double sr = 0.0, si = 0.0;
    for (int i = s0; i < s1; ++i) { sr += col[i].x; si += col[i].y; }
    double r = sr, im = si;
    #pragma unroll
    for (int off = 1; off < 64; off <<= 1) {
        double prx = __shfl_up(r, off);
        double piy = __shfl_up(im, off);
        if ((tid & 63) >= off) { r += prx; im += piy; }
    }
    if ((tid & 63) == 63) wsum[tid >> 6] = make_double2(r, im);
    __syncthreads();
    double basr = 0.0, basi = 0.0;
    int w = tid >> 6;
    for (int ww = 0; ww < w; ++ww) { basr += wsum[ww].x; basi += wsum[ww].y; }
    double gr = basr + r - sr, gi = basi + im - si;   // exclusive prefix at s0
    for (int i = s0; i < s1; ++i) {
        float qx = col[i].x, qy = col[i].y;
        col[i].x = (float)gr; col[i].y = (float)gi;
        gr += qx; gi += qy;
    }
    __syncthreads();

    int fi_, sg_; f_to_fi_sigma(f, fi_, sg_);
    float2* vrow = V + (size_t)f * VTP;
    #pragma unroll
    for (int k = 0; k < SEG; ++k) {
        int t = k * 512 + tid;
        if (t < T_FRAMES) {
            float4 ca = col[t];
            float4 cb = col[t + FULLBLK];
            float ur = cb.x - ca.x + cb.z;
            float ui = cb.y - ca.y + cb.w;
            unsigned ph = ((unsigned)fi_ * 128u * (unsigned)t) & 65535u;
            float frf = (float)ph * (1.0f / 65536.0f)
                      - (float)sg_ * (float)((128 * t) % MIN_WIN) * (1.0f / (float)MIN_WIN);
            frf -= rintf(frf);
            float sn, cs;
            __sincosf(TWOPI * frf, &sn, &cs);
            vrow[t] = make_float2(ur * cs - ui * sn, ur * sn + ui * cs);
        }
    }
}

// 16 frames/block (129 blocks): fold 3 planes (coalesced V reads along t) -> power
// -> interp -> log -> DCT -> fp64 atomic stats partials
#define TF16 16
__global__ __launch_bounds__(256) void k_cqt(const float2* __restrict__ V,
                                             float* __restrict__ cq,
                                             double* __restrict__ sums) {
    __shared__ float dctm[N_CQCC * N_BINS];     // 7680 B
    __shared__ float2 sc[F_COMP * TF16];        // [c][tl], 24,576 B
    __shared__ float lg[N_BINS * TF16];         // [b][tl], 6144 B
    __shared__ float cqv[N_CQCC * TF16];        // [k][tl], 1280 B
    int tid = threadIdx.x;
    int tb = blockIdx.x * TF16;
    for (int idx = tid; idx < N_CQCC * N_BINS; idx += 256) {
        int k = idx / N_BINS, b = idx - k * N_BINS;
        dctm[idx] = cosf((float)M_PI * (float)(k * (2 * b + 1)) / 192.0f);
    }
    // fold: idx = c*16 + tl; reads of V rows contiguous along t (128 B per row chunk)
    for (int idx = tid; idx < F_COMP * TF16; idx += 256) {
        int c = idx >> 4, tl = idx & 15;
        int t = tb + tl;
        float2 v = make_float2(0.f, 0.f);
        if (t < T_FRAMES) {
            float2 v0 = V[(size_t)c * VTP + t];
            float2 v1 = V[(size_t)(192 + c) * VTP + t];
            float2 v2 = V[(size_t)(384 + c) * VTP + t];
            v = make_float2(0.5f * v0.x - 0.25f * (v1.x + v2.x),
                            0.5f * v0.y - 0.25f * (v1.y + v2.y));
        }
        sc[idx] = v;
    }
    __syncthreads();
    for (int idx = tid; idx < N_BINS * TF16; idx += 256) {
        int b = idx >> 4, tl = idx & 15;
        float2 lo = sc[(2 * b) * TF16 + tl];
        float2 hi = sc[(2 * b + 1) * TF16 + tl];
        float pl = lo.x * lo.x + lo.y * lo.y;
        float ph = hi.x * hi.x + hi.y * hi.y;
        float e    = (float)b / 24.0f;
        float fb   = 32.7f * exp2f(e);
        float idxf = fb / 8000.0f * 32768.0f;
        float alpha = idxf - (float)((int)idxf);
        float p = (1.0f - alpha) * pl + alpha * ph;
        lg[idx] = logf(fmaxf(p, 1e-8f));
    }
    __syncthreads();
    for (int idx = tid; idx < N_CQCC * TF16; idx += 256) {
        int k = idx >> 4, tl = idx & 15;
        int t = tb + tl;
        float s = 0.0f;
        #pragma unroll 4
        for (int b = 0; b < N_BINS; ++b) s += dctm[k * N_BINS + b] * lg[b * TF16 + tl];
        cqv[idx] = (t < T_FRAMES) ? s : 0.0f;
        if (t < T_FRAMES) cq[t * N_CQCC + k] = s;
    }
    __syncthreads();
    if (tid < N_CQCC) {
        double s1 = 0.0, s2 = 0.0;
        #pragma unroll
        for (int tl = 0; tl < TF16; ++tl) {
            if (tb + tl < T_FRAMES) {
                double v = (double)cqv[tid * TF16 + tl];
                s1 += v; s2 += v * v;
            }
        }
        atomicAdd(&sums[tid], s1);
        atomicAdd(&sums[N_CQCC + tid], s2);
    }
}

__device__ __forceinline__ int clampT(int v) {
    return v < 0 ? 0 : (v > T_FRAMES - 1 ? T_FRAMES - 1 : v);
}

// normalize + delta + delta-delta; mean/inv derived inline from fp64 sums
__global__ void k_final(const float* __restrict__ cq, const double* __restrict__ sums,
                        float* __restrict__ out) {
    int gid = blockIdx.x * blockDim.x + threadIdx.x;
    if (gid >= T_FRAMES * N_CQCC) return;
    int t = gid / N_CQCC;
    int k = gid - t * N_CQCC;
    double S1 = sums[k], S2 = sums[N_CQCC + k];
    double md = S1 / (double)T_FRAMES;
    double var = (S2 - S1 * md) / (double)(T_FRAMES - 1);
    double sd = sqrt(var > 0.0 ? var : 0.0);
    float m = (float)md;
    float iv = (float)(1.0 / (sd + 1e-8));
    float cv[9];
    #pragma unroll
    for (int j = 0; j < 9; ++j)
        cv[j] = (cq[clampT(t + j - 4) * N_CQCC + k] - m) * iv;
    float dv[5];
    #pragma unroll
    for (int o = -2; o <= 2; ++o) {
        int p = clampT(t + o);
        int h1 = clampT(p + 1) - t, l1 = clampT(p - 1) - t;
        int h2 = clampT(p + 2) - t, l2 = clampT(p - 2) - t;
        dv[o + 2] = ((cv[h1 + 4] - cv[l1 + 4]) + 2.0f * (cv[h2 + 4] - cv[l2 + 4])) * 0.1f;
    }
    out[t * 60 + k]      = cv[4];
    out[t * 60 + 20 + k] = dv[2];
    out[t * 60 + 40 + k] = (dv[3] - dv[1] + 2.0f * (dv[4] - dv[0])) * 0.1f;
}

extern "C" void kernel_launch(void* const* d_in, const int* in_sizes, int n_in,
                              void* d_out, int out_size, void* d_ws, size_t ws_size,
                              hipStream_t stream) {
    const float* wav = (const float*)d_in[0];
    float* out = (float*)d_out;
    char* ws = (char*)d_ws;
    float4* QFP  = (float4*)(ws + WS_QFP);
    float2* V    = (float2*)(ws + WS_V);
    float*  cq   = (float*)(ws + WS_CQ);
    double* sums = (double*)(ws + WS_SUMS);

    k_chunk<<<dim3(NBP / BT, NF / FTW), 256, 0, stream>>>(wav, QFP);
    k_scan<<<NF, 512, 0, stream>>>(QFP, V, sums);
    k_cqt<<<(T_FRAMES + TF16 - 1) / TF16, 256, 0, stream>>>(V, cq, sums);
    k_final<<<(T_FRAMES * N_CQCC + 255) / 256, 256, 0, stream>>>(cq, sums, out);
}